// Round 16
// baseline (286.256 us; speedup 1.0000x reference)
//
#include <hip/hip_runtime.h>
#include <hip/hip_bf16.h>

typedef __bf16 bf16x8 __attribute__((ext_vector_type(8)));
typedef float f32x4 __attribute__((ext_vector_type(4)));
typedef unsigned short u16;

constexpr int BATCH = 2, SEQ = 2048, DM = 2048, NH = 16, HD = 128;
constexpr int N3 = 3 * DM;          // 6144
constexpr int MROWS = BATCH * SEQ;  // 4096

__device__ __forceinline__ u16 f2bf(float f) {
  unsigned u = __builtin_bit_cast(unsigned, f);
  unsigned r = 0x7FFFu + ((u >> 16) & 1u);
  return (u16)((u + r) >> 16);
}

// async global->LDS, 16B per lane; LDS dest = wave-uniform base + lane*16
__device__ __forceinline__ void glds16(const u16* g, u16* l) {
  __builtin_amdgcn_global_load_lds(
      (const __attribute__((address_space(1))) unsigned*)(const void*)g,
      (__attribute__((address_space(3))) unsigned*)(void*)l, 16, 0, 0);
}

// ---------------- convert f32 -> bf16 (n4 = n/4 float4 groups) ----------------
__global__ __launch_bounds__(256) void k_cvt(const float* __restrict__ in,
                                             u16* __restrict__ out, int n4) {
  int i = blockIdx.x * blockDim.x + threadIdx.x;
  if (i >= n4) return;
  float4 v = reinterpret_cast<const float4*>(in)[i];
  ushort4 o;
  o.x = f2bf(v.x); o.y = f2bf(v.y); o.z = f2bf(v.z); o.w = f2bf(v.w);
  reinterpret_cast<ushort4*>(out)[i] = o;
}

// ---------------- transpose f32 [K][N] -> bf16 [N][K] ----------------
__global__ __launch_bounds__(256) void k_transpose(const float* __restrict__ in,
                                                   u16* __restrict__ out, int K, int N) {
  __shared__ float tile[32][33];
  int n0 = blockIdx.x * 32, k0 = blockIdx.y * 32;
  int tx = threadIdx.x & 31, ty = threadIdx.x >> 5;  // 32 x 8
#pragma unroll
  for (int r = ty; r < 32; r += 8) tile[r][tx] = in[(long)(k0 + r) * N + n0 + tx];
  __syncthreads();
#pragma unroll
  for (int r = ty; r < 32; r += 8) out[(long)(n0 + r) * K + k0 + tx] = f2bf(tile[tx][r]);
}

// ---------------- QKV GEMM: 128x192 tile, BK=64, 4 waves, 4-PHASE, 2 blocks/CU ----------------
__global__ __launch_bounds__(256, 2) void k_gemm_qkv(const u16* __restrict__ A,
                                                     const u16* __restrict__ Bt,
                                                     const float* __restrict__ bias,
                                                     u16* __restrict__ Qb, u16* __restrict__ Kb,
                                                     u16* __restrict__ Vt) {
  constexpr int K = DM;        // 2048
  constexpr int NKT = K / 64;  // 32 K-tiles
  constexpr int NIT = NKT / 2; // 16 iterations
  __shared__ u16 LA[2 * 128 * 64];  // 32 KB
  __shared__ u16 LB[2 * 192 * 64];  // 48 KB
  int lin = blockIdx.y * 32 + blockIdx.x;
  int wid = (lin & 7) * 128 + (lin >> 3);
  int m0 = (wid & 31) * 128;
  int n0 = (wid >> 5) * 192;
  int t = threadIdx.x, lane = t & 63, w = t >> 6;
  int l15 = lane & 15, lhi = lane >> 4;
  int wrow = w >> 1, wcol = w & 1;  // 2x2 wave grid; per-wave out 64x96
  int srow = t >> 3;                       // 0..31
  int scol = ((t & 7) ^ (srow & 7)) * 8;

#define STG_A(TILE, IDX) do {                                                      \
    int kb_ = ((TILE) < NKT ? (TILE) : NKT - 1) * 64;                              \
    glds16(A + (long)(m0 + (IDX) * 32 + srow) * K + kb_ + scol,                    \
           LA + ((TILE) & 1) * 8192 + (IDX) * 2048 + w * 512);                     \
  } while (0)
#define STG_B(TILE, IDX) do {                                                      \
    int kb_ = ((TILE) < NKT ? (TILE) : NKT - 1) * 64;                              \
    glds16(Bt + (long)(n0 + (IDX) * 32 + srow) * K + kb_ + scol,                   \
           LB + ((TILE) & 1) * 12288 + (IDX) * 2048 + w * 512);                    \
  } while (0)

  bf16x8 af2[4][2], bfr0[3][2], bfr1[3][2];
  f32x4 acc[4][6] = {};

#define LDA_ALL(BUF) do {                                                          \
    _Pragma("unroll") for (int mi = 0; mi < 4; mi++) {                             \
      int rA = wrow * 64 + mi * 16 + l15;                                          \
      _Pragma("unroll") for (int kk = 0; kk < 2; kk++)                             \
        af2[mi][kk] = *(const bf16x8*)(LA + (BUF) * 8192 + rA * 64 +               \
                                       (((kk * 4 + lhi) ^ (rA & 7)) * 8));         \
    } } while (0)
#define LDB_FRAGS(BUF, QN, DST) do {                                               \
    _Pragma("unroll") for (int ni = 0; ni < 3; ni++) {                             \
      int rB = wcol * 96 + ((QN) * 3 + ni) * 16 + l15;                             \
      _Pragma("unroll") for (int kk = 0; kk < 2; kk++)                             \
        DST[ni][kk] = *(const bf16x8*)(LB + (BUF) * 12288 + rB * 64 +              \
                                       (((kk * 4 + lhi) ^ (rB & 7)) * 8));         \
    } } while (0)
#define MM2Q(QN, BF) do {                                                          \
    __builtin_amdgcn_s_setprio(1);                                                 \
    _Pragma("unroll") for (int mi = 0; mi < 4; mi++)                               \
    _Pragma("unroll") for (int ni = 0; ni < 3; ni++)                               \
    _Pragma("unroll") for (int kk = 0; kk < 2; kk++)                               \
      acc[mi][(QN) * 3 + ni] = __builtin_amdgcn_mfma_f32_16x16x32_bf16(            \
          af2[mi][kk], BF[ni][kk], acc[mi][(QN) * 3 + ni], 0, 0, 0);               \
    __builtin_amdgcn_s_setprio(0);                                                 \
  } while (0)
#define BAR __builtin_amdgcn_s_barrier()
#define LG0 do { asm volatile("s_waitcnt lgkmcnt(0)" ::: "memory");                \
                 __builtin_amdgcn_sched_barrier(0); } while (0)
#define VMW6 do { asm volatile("s_waitcnt vmcnt(6)" ::: "memory");                 \
                  __builtin_amdgcn_sched_barrier(0); } while (0)

  STG_A(0, 0); STG_A(0, 1); STG_A(0, 2); STG_A(0, 3);
  STG_B(0, 0); STG_B(0, 1); STG_B(0, 2); STG_B(0, 3); STG_B(0, 4); STG_B(0, 5);
  STG_B(1, 0); STG_B(1, 1); STG_B(1, 2); STG_B(1, 3); STG_B(1, 4); STG_B(1, 5);
  VMW6; BAR;

  for (int it = 0; it < NIT; it++) {
    int k1 = 2 * it + 1, k2 = 2 * it + 2, k3 = 2 * it + 3;
    LDA_ALL(0); LDB_FRAGS(0, 0, bfr0);
    STG_A(k1, 0); STG_A(k1, 1); STG_A(k1, 2); STG_A(k1, 3);
    BAR; LG0; MM2Q(0, bfr0); BAR;                                    // phA
    LDB_FRAGS(0, 1, bfr1);
    STG_B(k2, 0); STG_B(k2, 1); STG_B(k2, 2);
    STG_B(k2, 3); STG_B(k2, 4); STG_B(k2, 5);
    VMW6;
    BAR; LG0; MM2Q(1, bfr1); BAR;                                    // phB
    LDA_ALL(1); LDB_FRAGS(1, 0, bfr0);
    STG_A(k2, 0); STG_A(k2, 1); STG_A(k2, 2); STG_A(k2, 3);
    BAR; LG0; MM2Q(0, bfr0); BAR;                                    // phC
    LDB_FRAGS(1, 1, bfr1);
    STG_B(k3, 0); STG_B(k3, 1); STG_B(k3, 2);
    STG_B(k3, 3); STG_B(k3, 4); STG_B(k3, 5);
    VMW6;
    BAR; LG0; MM2Q(1, bfr1); BAR;                                    // phD
  }
#undef STG_A
#undef STG_B
#undef LDA_ALL
#undef LDB_FRAGS
#undef MM2Q
#undef BAR
#undef LG0
#undef VMW6

#pragma unroll
  for (int mi = 0; mi < 4; mi++)
#pragma unroll
    for (int ni = 0; ni < 6; ni++) {
      int col = n0 + wcol * 96 + ni * 16 + l15;
      float bv = bias[col];
      int sec = col >> 11, dn = col & 2047, h = dn >> 7, hd = dn & 127;
#pragma unroll
      for (int r = 0; r < 4; r++) {
        int row = m0 + wrow * 64 + mi * 16 + lhi * 4 + r;
        int bb = row >> 11, ss = row & 2047;
        u16 val = f2bf(acc[mi][ni][r] + bv);
        if (sec == 0)
          Qb[(((long)(bb * NH + h)) * SEQ + ss) * HD + hd] = val;
        else if (sec == 1)
          Kb[(((long)(bb * NH + h)) * SEQ + ss) * HD + hd] = val;
        else
          Vt[(((long)(bb * NH + h)) * HD + hd) * SEQ + ss] = val;
      }
    }
}

// ---------------- output GEMM: 128x128 tile, BK=64, 4 waves, 4-PHASE, 2 blocks/CU ----------------
__global__ __launch_bounds__(256, 2) void k_gemm_out(const u16* __restrict__ A,
                                                     const u16* __restrict__ Bt,
                                                     const float* __restrict__ bias,
                                                     float* __restrict__ Out) {
  constexpr int K = DM, N = DM;
  constexpr int NKT = K / 64;  // 32
  constexpr int NIT = NKT / 2; // 16
  __shared__ u16 LA[2 * 128 * 64];  // 32 KB
  __shared__ u16 LB[2 * 128 * 64];  // 32 KB
  int lin = blockIdx.y * 16 + blockIdx.x;
  int wid = (lin & 7) * 64 + (lin >> 3);
  int m0 = (wid & 31) * 128;
  int n0 = (wid >> 5) * 128;
  int t = threadIdx.x, lane = t & 63, w = t >> 6;
  int l15 = lane & 15, lhi = lane >> 4;
  int wrow = w >> 1, wcol = w & 1;  // 2x2 waves; per-wave out 64x64
  int srow = t >> 3;                // 0..31
  int scol = ((t & 7) ^ (srow & 7)) * 8;

#define STG_A(TILE, IDX) do {                                                      \
    int kb_ = ((TILE) < NKT ? (TILE) : NKT - 1) * 64;                              \
    glds16(A + (long)(m0 + (IDX) * 32 + srow) * K + kb_ + scol,                    \
           LA + ((TILE) & 1) * 8192 + (IDX) * 2048 + w * 512);                     \
  } while (0)
#define STG_B(TILE, IDX) do {                                                      \
    int kb_ = ((TILE) < NKT ? (TILE) : NKT - 1) * 64;                              \
    glds16(Bt + (long)(n0 + (IDX) * 32 + srow) * K + kb_ + scol,                   \
           LB + ((TILE) & 1) * 8192 + (IDX) * 2048 + w * 512);                     \
  } while (0)

  bf16x8 af2[4][2], bfr0[2][2], bfr1[2][2];
  f32x4 acc[4][4] = {};

#define LDA_ALL(BUF) do {                                                          \
    _Pragma("unroll") for (int mi = 0; mi < 4; mi++) {                             \
      int rA = wrow * 64 + mi * 16 + l15;                                          \
      _Pragma("unroll") for (int kk = 0; kk < 2; kk++)                             \
        af2[mi][kk] = *(const bf16x8*)(LA + (BUF) * 8192 + rA * 64 +               \
                                       (((kk * 4 + lhi) ^ (rA & 7)) * 8));         \
    } } while (0)
#define LDB_FRAGS(BUF, QN, DST) do {                                               \
    _Pragma("unroll") for (int ni = 0; ni < 2; ni++) {                             \
      int rB = wcol * 64 + ((QN) * 2 + ni) * 16 + l15;                             \
      _Pragma("unroll") for (int kk = 0; kk < 2; kk++)                             \
        DST[ni][kk] = *(const bf16x8*)(LB + (BUF) * 8192 + rB * 64 +               \
                                       (((kk * 4 + lhi) ^ (rB & 7)) * 8));         \
    } } while (0)
#define MM2Q(QN, BF) do {                                                          \
    __builtin_amdgcn_s_setprio(1);                                                 \
    _Pragma("unroll") for (int mi = 0; mi < 4; mi++)                               \
    _Pragma("unroll") for (int ni = 0; ni < 2; ni++)                               \
    _Pragma("unroll") for (int kk = 0; kk < 2; kk++)                               \
      acc[mi][(QN) * 2 + ni] = __builtin_amdgcn_mfma_f32_16x16x32_bf16(            \
          af2[mi][kk], BF[ni][kk], acc[mi][(QN) * 2 + ni], 0, 0, 0);               \
    __builtin_amdgcn_s_setprio(0);                                                 \
  } while (0)
#define BAR __builtin_amdgcn_s_barrier()
#define LG0 do { asm volatile("s_waitcnt lgkmcnt(0)" ::: "memory");                \
                 __builtin_amdgcn_sched_barrier(0); } while (0)
#define VMW4 do { asm volatile("s_waitcnt vmcnt(4)" ::: "memory");                 \
                  __builtin_amdgcn_sched_barrier(0); } while (0)

  STG_A(0, 0); STG_A(0, 1); STG_A(0, 2); STG_A(0, 3);
  STG_B(0, 0); STG_B(0, 1); STG_B(0, 2); STG_B(0, 3);
  STG_B(1, 0); STG_B(1, 1); STG_B(1, 2); STG_B(1, 3);
  VMW4; BAR;

  for (int it = 0; it < NIT; it++) {
    int k1 = 2 * it + 1, k2 = 2 * it + 2, k3 = 2 * it + 3;
    LDA_ALL(0); LDB_FRAGS(0, 0, bfr0);
    STG_A(k1, 0); STG_A(k1, 1); STG_A(k1, 2); STG_A(k1, 3);
    BAR; LG0; MM2Q(0, bfr0); BAR;                                    // phA
    LDB_FRAGS(0, 1, bfr1);
    STG_B(k2, 0); STG_B(k2, 1); STG_B(k2, 2); STG_B(k2, 3);
    VMW4;
    BAR; LG0; MM2Q(1, bfr1); BAR;                                    // phB
    LDA_ALL(1); LDB_FRAGS(1, 0, bfr0);
    STG_A(k2, 0); STG_A(k2, 1); STG_A(k2, 2); STG_A(k2, 3);
    BAR; LG0; MM2Q(0, bfr0); BAR;                                    // phC
    LDB_FRAGS(1, 1, bfr1);
    STG_B(k3, 0); STG_B(k3, 1); STG_B(k3, 2); STG_B(k3, 3);
    VMW4;
    BAR; LG0; MM2Q(1, bfr1); BAR;                                    // phD
  }
#undef STG_A
#undef STG_B
#undef LDA_ALL
#undef LDB_FRAGS
#undef MM2Q
#undef BAR
#undef LG0
#undef VMW4

#pragma unroll
  for (int mi = 0; mi < 4; mi++)
#pragma unroll
    for (int ni = 0; ni < 4; ni++) {
      int col = n0 + wcol * 64 + ni * 16 + l15;
      float bv = bias[col];
#pragma unroll
      for (int r = 0; r < 4; r++) {
        int row = m0 + wrow * 64 + mi * 16 + lhi * 4 + r;
        Out[(long)row * N + col] = acc[mi][ni][r] + bv;
      }
    }
}

// ---------------- flash attention: QBLK=128, 8 waves share one KV stream ----------------
// 512 threads; wave w owns q rows [qb*128 + w*16, +16). KV traffic halved vs QBLK=64.
// Grid 32 x 16 = 512 blocks @ 80KB LDS -> 2 blocks/CU = 1 exact round, LPT order.
// Causal: tiles kt >= nt-2 apply the mask (upper-wave final tile fully masks -> exp=0).
// NO min-waves launch bound (R10 lesson); per-wave VGPR state identical to QBLK=64 version.
__global__ __launch_bounds__(512) void k_attn(const u16* __restrict__ Qb,
                                              const u16* __restrict__ Kb,
                                              const u16* __restrict__ Vt,
                                              const float* __restrict__ mask,
                                              u16* __restrict__ Ao) {
  constexpr int NQB = SEQ / 128;   // 16 q-blocks
  int bh = blockIdx.x;             // b*NH + h
  int qb = (NQB - 1) - blockIdx.y; // longest first (LPT)
  int t = threadIdx.x, w = t >> 6, lane = t & 63;
  int l15 = lane & 15, lhi = lane >> 4;
  int b = bh >> 4, h = bh & 15;
  const u16* Qh = Qb + (long)bh * SEQ * HD;
  const u16* Kh = Kb + (long)bh * SEQ * HD;
  const u16* Vh = Vt + (long)bh * HD * SEQ;
  const float* mh = mask + h * SEQ;

  __shared__ u16 Ks[2][64 * 128];   // 32 KB
  __shared__ u16 Vs[2][128 * 64];   // 32 KB
  __shared__ u16 p_lds[8 * 16 * 64];  // 16 KB
  u16* pw = p_lds + w * (16 * 64);

  // staging: 512 threads x 2 chunks of 16B per 16KB tile; source col pre-swizzled
  int krow[2], kcolS[2], vrow[2], vcolS[2];
#pragma unroll
  for (int i = 0; i < 2; i++) {
    int c = i * 512 + t;
    krow[i] = c >> 4; kcolS[i] = ((c & 15) ^ ((c >> 4) & 7)) * 8;   // K: 64 x 128
    vrow[i] = c >> 3; vcolS[i] = ((c & 7) ^ ((c >> 3) & 7)) * 8;    // V: 128 x 64
  }

#define STAGE(KT, BUF) do {                                                        \
    int kb_ = (KT) * 64;                                                           \
    _Pragma("unroll") for (int i = 0; i < 2; i++)                                  \
      glds16(Kh + (long)(kb_ + krow[i]) * HD + kcolS[i],                           \
             &Ks[BUF][(i * 512 + w * 64) * 8]);                                    \
    _Pragma("unroll") for (int i = 0; i < 2; i++)                                  \
      glds16(Vh + (long)vrow[i] * SEQ + kb_ + vcolS[i],                            \
             &Vs[BUF][(i * 512 + w * 64) * 8]);                                    \
  } while (0)

  const float sm_scale = 0.08838834764831845f;  // 1/sqrt(128)
  int q0 = qb * 128 + w * 16;
  int nt = 2 * qb + 2;  // 64-wide KV tiles covering keys < (qb+1)*128

  bf16x8 qf[4];
#pragma unroll
  for (int kc = 0; kc < 4; kc++)
    qf[kc] = *(const bf16x8*)(Qh + (long)(q0 + l15) * HD + kc * 32 + lhi * 8);

  float mrun[4], lrun[4];
  f32x4 oacc[8] = {};
#pragma unroll
  for (int r = 0; r < 4; r++) { mrun[r] = -1e30f; lrun[r] = 0.f; }

  STAGE(0, 0);
  __syncthreads();  // drains vmcnt: tile 0 resident

  for (int kt = 0; kt < nt; kt++) {
    int cur = kt & 1;
    if (kt + 1 < nt) STAGE(kt + 1, cur ^ 1);  // async into other buffer
    bool maskt = (kt >= nt - 2);  // last two tiles intersect the 128-row diagonal band
    int kb = kt * 64;
    const u16* Ksg = Ks[cur];
    const u16* Vsg = Vs[cur];
    float bvv[4];
#pragma unroll
    for (int cb = 0; cb < 4; cb++) bvv[cb] = mh[kb + cb * 16 + l15];
    f32x4 sc[4] = {};
    __builtin_amdgcn_s_setprio(1);
#pragma unroll
    for (int kc = 0; kc < 4; kc++)
#pragma unroll
      for (int cb = 0; cb < 4; cb++) {
        int rr = cb * 16 + l15;
        bf16x8 kf = *(const bf16x8*)(Ksg + rr * 128 + ((kc * 32 + lhi * 8) ^ ((rr & 7) << 3)));
        sc[cb] = __builtin_amdgcn_mfma_f32_16x16x32_bf16(qf[kc], kf, sc[cb], 0, 0, 0);
      }
    __builtin_amdgcn_s_setprio(0);
    float p[4][4], tmax[4];
#pragma unroll
    for (int cb = 0; cb < 4; cb++) {
      int col = kb + cb * 16 + l15;
#pragma unroll
      for (int r = 0; r < 4; r++) {
        float v = sc[cb][r] * sm_scale + bvv[cb];
        if (maskt) v = (col <= q0 + lhi * 4 + r) ? v : -1e30f;
        p[cb][r] = v;
      }
    }
#pragma unroll
    for (int r = 0; r < 4; r++)
      tmax[r] = fmaxf(fmaxf(p[0][r], p[1][r]), fmaxf(p[2][r], p[3][r]));
    float alpha[4];
#pragma unroll
    for (int r = 0; r < 4; r++) {
      float v = tmax[r];
      v = fmaxf(v, __shfl_xor(v, 1));
      v = fmaxf(v, __shfl_xor(v, 2));
      v = fmaxf(v, __shfl_xor(v, 4));
      v = fmaxf(v, __shfl_xor(v, 8));
      float mnew = fmaxf(mrun[r], v);
      alpha[r] = __expf(mrun[r] - mnew);
      mrun[r] = mnew;
      float s = 0.f;
#pragma unroll
      for (int cb = 0; cb < 4; cb++) {
        float e = __expf(p[cb][r] - mnew);
        p[cb][r] = e;
        s += e;
      }
      s += __shfl_xor(s, 1); s += __shfl_xor(s, 2);
      s += __shfl_xor(s, 4); s += __shfl_xor(s, 8);
      lrun[r] = lrun[r] * alpha[r] + s;
    }
#pragma unroll
    for (int nb = 0; nb < 8; nb++)
#pragma unroll
      for (int r = 0; r < 4; r++) oacc[nb][r] *= alpha[r];
#pragma unroll
    for (int cb = 0; cb < 4; cb++)
#pragma unroll
      for (int r = 0; r < 4; r++) {
        int rr = lhi * 4 + r;
        pw[(rr * 64 + cb * 16 + l15) ^ ((rr & 7) << 3)] = f2bf(p[cb][r]);
      }
    asm volatile("s_waitcnt lgkmcnt(0)" ::: "memory");
    bf16x8 pa0 = *(const bf16x8*)(pw + ((l15 * 64 + lhi * 8) ^ ((l15 & 7) << 3)));
    bf16x8 pa1 = *(const bf16x8*)(pw + ((l15 * 64 + 32 + lhi * 8) ^ ((l15 & 7) << 3)));
    __builtin_amdgcn_s_setprio(1);
#pragma unroll
    for (int nb = 0; nb < 8; nb++) {
      int rr = nb * 16 + l15;
      bf16x8 vf0 = *(const bf16x8*)(Vsg + rr * 64 + ((lhi * 8) ^ ((rr & 7) << 3)));
      bf16x8 vf1 = *(const bf16x8*)(Vsg + rr * 64 + ((32 + lhi * 8) ^ ((rr & 7) << 3)));
      oacc[nb] = __builtin_amdgcn_mfma_f32_16x16x32_bf16(pa0, vf0, oacc[nb], 0, 0, 0);
      oacc[nb] = __builtin_amdgcn_mfma_f32_16x16x32_bf16(pa1, vf1, oacc[nb], 0, 0, 0);
    }
    __builtin_amdgcn_s_setprio(0);
    __syncthreads();  // all reads of buf cur done; drains staged loads for buf cur^1
  }
#pragma unroll
  for (int nb = 0; nb < 8; nb++)
#pragma unroll
    for (int r = 0; r < 4; r++) {
      int row = q0 + lhi * 4 + r;
      float v = oacc[nb][r] / lrun[r];
      Ao[((long)(b * SEQ + row)) * DM + h * HD + nb * 16 + l15] = f2bf(v);
    }
#undef STAGE
}

// ---------------- launcher ----------------
extern "C" void kernel_launch(void* const* d_in, const int* in_sizes, int n_in,
                              void* d_out, int out_size, void* d_ws, size_t ws_size,
                              hipStream_t stream) {
  const float* x    = (const float*)d_in[0];
  const float* amsk = (const float*)d_in[1];
  const float* Wqkv = (const float*)d_in[2];
  const float* bqkv = (const float*)d_in[3];
  const float* Wout = (const float*)d_in[4];
  const float* bout = (const float*)d_in[5];
  float* out = (float*)d_out;

  char* ws = (char*)d_ws;
  u16* xb  = (u16*)(ws + 0);                   // [4096][2048]
  u16* WqT = (u16*)(ws + 16777216UL);          // [6144][2048]
  u16* WoT = (u16*)(ws + 41943040UL);          // [2048][2048]
  u16* Qb  = (u16*)(ws + 50331648UL);          // [B*H][S][HD]
  u16* Kb  = (u16*)(ws + 67108864UL);          // [B*H][S][HD]
  u16* Vt  = (u16*)(ws + 83886080UL);          // [B*H][HD][S]
  u16* Ao  = (u16*)(ws + 100663296UL);         // [4096][2048]

  k_cvt<<<8192, 256, 0, stream>>>(x, xb, (MROWS * DM) / 4);
  k_transpose<<<dim3(N3 / 32, DM / 32), 256, 0, stream>>>(Wqkv, WqT, DM, N3);
  k_transpose<<<dim3(DM / 32, DM / 32), 256, 0, stream>>>(Wout, WoT, DM, DM);
  k_gemm_qkv<<<dim3(32, 32), 256, 0, stream>>>(xb, WqT, bqkv, Qb, Kb, Vt);
  k_attn<<<dim3(BATCH * NH, SEQ / 128), 512, 0, stream>>>(Qb, Kb, Vt, amsk, Ao);
  k_gemm_out<<<dim3(16, 32), 256, 0, stream>>>(Ao, WoT, bout, out);
}

// Round 17
// 279.326 us; speedup vs baseline: 1.0248x; 1.0248x over previous
//
#include <hip/hip_runtime.h>
#include <hip/hip_bf16.h>

typedef __bf16 bf16x8 __attribute__((ext_vector_type(8)));
typedef float f32x4 __attribute__((ext_vector_type(4)));
typedef unsigned short u16;

constexpr int BATCH = 2, SEQ = 2048, DM = 2048, NH = 16, HD = 128;
constexpr int N3 = 3 * DM;          // 6144
constexpr int MROWS = BATCH * SEQ;  // 4096

__device__ __forceinline__ u16 f2bf(float f) {
  unsigned u = __builtin_bit_cast(unsigned, f);
  unsigned r = 0x7FFFu + ((u >> 16) & 1u);
  return (u16)((u + r) >> 16);
}

// async global->LDS, 16B per lane; LDS dest = wave-uniform base + lane*16
__device__ __forceinline__ void glds16(const u16* g, u16* l) {
  __builtin_amdgcn_global_load_lds(
      (const __attribute__((address_space(1))) unsigned*)(const void*)g,
      (__attribute__((address_space(3))) unsigned*)(void*)l, 16, 0, 0);
}

// ---------------- convert f32 -> bf16 (n4 = n/4 float4 groups) ----------------
__global__ __launch_bounds__(256) void k_cvt(const float* __restrict__ in,
                                             u16* __restrict__ out, int n4) {
  int i = blockIdx.x * blockDim.x + threadIdx.x;
  if (i >= n4) return;
  float4 v = reinterpret_cast<const float4*>(in)[i];
  ushort4 o;
  o.x = f2bf(v.x); o.y = f2bf(v.y); o.z = f2bf(v.z); o.w = f2bf(v.w);
  reinterpret_cast<ushort4*>(out)[i] = o;
}

// ---------------- transpose f32 [K][N] -> bf16 [N][K] ----------------
__global__ __launch_bounds__(256) void k_transpose(const float* __restrict__ in,
                                                   u16* __restrict__ out, int K, int N) {
  __shared__ float tile[32][33];
  int n0 = blockIdx.x * 32, k0 = blockIdx.y * 32;
  int tx = threadIdx.x & 31, ty = threadIdx.x >> 5;  // 32 x 8
#pragma unroll
  for (int r = ty; r < 32; r += 8) tile[r][tx] = in[(long)(k0 + r) * N + n0 + tx];
  __syncthreads();
#pragma unroll
  for (int r = ty; r < 32; r += 8) out[(long)(n0 + r) * K + k0 + tx] = f2bf(tile[tx][r]);
}

// ---------------- QKV GEMM: 128x192 tile, BK=64, 4 waves, 4-PHASE, 2 blocks/CU ----------------
// R17: VMW6 moved AFTER the MFMA cluster (before closing BAR) — the loads it completes
// are first consumed next phase; waiting before the MM exposed A(k1)'s load latency.
__global__ __launch_bounds__(256, 2) void k_gemm_qkv(const u16* __restrict__ A,
                                                     const u16* __restrict__ Bt,
                                                     const float* __restrict__ bias,
                                                     u16* __restrict__ Qb, u16* __restrict__ Kb,
                                                     u16* __restrict__ Vt) {
  constexpr int K = DM;        // 2048
  constexpr int NKT = K / 64;  // 32 K-tiles
  constexpr int NIT = NKT / 2; // 16 iterations
  __shared__ u16 LA[2 * 128 * 64];  // 32 KB
  __shared__ u16 LB[2 * 192 * 64];  // 48 KB
  int lin = blockIdx.y * 32 + blockIdx.x;
  int wid = (lin & 7) * 128 + (lin >> 3);
  int m0 = (wid & 31) * 128;
  int n0 = (wid >> 5) * 192;
  int t = threadIdx.x, lane = t & 63, w = t >> 6;
  int l15 = lane & 15, lhi = lane >> 4;
  int wrow = w >> 1, wcol = w & 1;  // 2x2 wave grid; per-wave out 64x96
  int srow = t >> 3;                       // 0..31
  int scol = ((t & 7) ^ (srow & 7)) * 8;

#define STG_A(TILE, IDX) do {                                                      \
    int kb_ = ((TILE) < NKT ? (TILE) : NKT - 1) * 64;                              \
    glds16(A + (long)(m0 + (IDX) * 32 + srow) * K + kb_ + scol,                    \
           LA + ((TILE) & 1) * 8192 + (IDX) * 2048 + w * 512);                     \
  } while (0)
#define STG_B(TILE, IDX) do {                                                      \
    int kb_ = ((TILE) < NKT ? (TILE) : NKT - 1) * 64;                              \
    glds16(Bt + (long)(n0 + (IDX) * 32 + srow) * K + kb_ + scol,                   \
           LB + ((TILE) & 1) * 12288 + (IDX) * 2048 + w * 512);                    \
  } while (0)

  bf16x8 af2[4][2], bfr0[3][2], bfr1[3][2];
  f32x4 acc[4][6] = {};

#define LDA_ALL(BUF) do {                                                          \
    _Pragma("unroll") for (int mi = 0; mi < 4; mi++) {                             \
      int rA = wrow * 64 + mi * 16 + l15;                                          \
      _Pragma("unroll") for (int kk = 0; kk < 2; kk++)                             \
        af2[mi][kk] = *(const bf16x8*)(LA + (BUF) * 8192 + rA * 64 +               \
                                       (((kk * 4 + lhi) ^ (rA & 7)) * 8));         \
    } } while (0)
#define LDB_FRAGS(BUF, QN, DST) do {                                               \
    _Pragma("unroll") for (int ni = 0; ni < 3; ni++) {                             \
      int rB = wcol * 96 + ((QN) * 3 + ni) * 16 + l15;                             \
      _Pragma("unroll") for (int kk = 0; kk < 2; kk++)                             \
        DST[ni][kk] = *(const bf16x8*)(LB + (BUF) * 12288 + rB * 64 +              \
                                       (((kk * 4 + lhi) ^ (rB & 7)) * 8));         \
    } } while (0)
#define MM2Q(QN, BF) do {                                                          \
    __builtin_amdgcn_s_setprio(1);                                                 \
    _Pragma("unroll") for (int mi = 0; mi < 4; mi++)                               \
    _Pragma("unroll") for (int ni = 0; ni < 3; ni++)                               \
    _Pragma("unroll") for (int kk = 0; kk < 2; kk++)                               \
      acc[mi][(QN) * 3 + ni] = __builtin_amdgcn_mfma_f32_16x16x32_bf16(            \
          af2[mi][kk], BF[ni][kk], acc[mi][(QN) * 3 + ni], 0, 0, 0);               \
    __builtin_amdgcn_s_setprio(0);                                                 \
  } while (0)
#define BAR __builtin_amdgcn_s_barrier()
#define LG0 do { asm volatile("s_waitcnt lgkmcnt(0)" ::: "memory");                \
                 __builtin_amdgcn_sched_barrier(0); } while (0)
#define VMW6 do { asm volatile("s_waitcnt vmcnt(6)" ::: "memory");                 \
                  __builtin_amdgcn_sched_barrier(0); } while (0)

  STG_A(0, 0); STG_A(0, 1); STG_A(0, 2); STG_A(0, 3);
  STG_B(0, 0); STG_B(0, 1); STG_B(0, 2); STG_B(0, 3); STG_B(0, 4); STG_B(0, 5);
  STG_B(1, 0); STG_B(1, 1); STG_B(1, 2); STG_B(1, 3); STG_B(1, 4); STG_B(1, 5);
  VMW6; BAR;

  for (int it = 0; it < NIT; it++) {
    int k1 = 2 * it + 1, k2 = 2 * it + 2, k3 = 2 * it + 3;
    // ---- K-tile 2it (buf0) ----
    LDA_ALL(0); LDB_FRAGS(0, 0, bfr0);
    STG_A(k1, 0); STG_A(k1, 1); STG_A(k1, 2); STG_A(k1, 3);
    BAR; LG0; MM2Q(0, bfr0); BAR;                                    // phA
    LDB_FRAGS(0, 1, bfr1);
    STG_B(k2, 0); STG_B(k2, 1); STG_B(k2, 2);
    STG_B(k2, 3); STG_B(k2, 4); STG_B(k2, 5);
    BAR; LG0; MM2Q(1, bfr1);
    VMW6;  // completes B(k1)+A(k1) (consumed at phC); waits AFTER MM for max cover
    BAR;                                                             // phB
    // ---- K-tile 2it+1 (buf1) ----
    LDA_ALL(1); LDB_FRAGS(1, 0, bfr0);
    STG_A(k2, 0); STG_A(k2, 1); STG_A(k2, 2); STG_A(k2, 3);
    BAR; LG0; MM2Q(0, bfr0); BAR;                                    // phC
    LDB_FRAGS(1, 1, bfr1);
    STG_B(k3, 0); STG_B(k3, 1); STG_B(k3, 2);
    STG_B(k3, 3); STG_B(k3, 4); STG_B(k3, 5);
    BAR; LG0; MM2Q(1, bfr1);
    VMW6;  // completes B(k2)+A(k2) for next iter's phA
    BAR;                                                             // phD
  }
#undef STG_A
#undef STG_B
#undef LDA_ALL
#undef LDB_FRAGS
#undef MM2Q
#undef BAR
#undef LG0
#undef VMW6

#pragma unroll
  for (int mi = 0; mi < 4; mi++)
#pragma unroll
    for (int ni = 0; ni < 6; ni++) {
      int col = n0 + wcol * 96 + ni * 16 + l15;
      float bv = bias[col];
      int sec = col >> 11, dn = col & 2047, h = dn >> 7, hd = dn & 127;
#pragma unroll
      for (int r = 0; r < 4; r++) {
        int row = m0 + wrow * 64 + mi * 16 + lhi * 4 + r;
        int bb = row >> 11, ss = row & 2047;
        u16 val = f2bf(acc[mi][ni][r] + bv);
        if (sec == 0)
          Qb[(((long)(bb * NH + h)) * SEQ + ss) * HD + hd] = val;
        else if (sec == 1)
          Kb[(((long)(bb * NH + h)) * SEQ + ss) * HD + hd] = val;
        else
          Vt[(((long)(bb * NH + h)) * HD + hd) * SEQ + ss] = val;
      }
    }
}

// ---------------- output GEMM: 128x128 tile, BK=64, 4 waves, 4-PHASE, 2 blocks/CU ----------------
__global__ __launch_bounds__(256, 2) void k_gemm_out(const u16* __restrict__ A,
                                                     const u16* __restrict__ Bt,
                                                     const float* __restrict__ bias,
                                                     float* __restrict__ Out) {
  constexpr int K = DM, N = DM;
  constexpr int NKT = K / 64;  // 32
  constexpr int NIT = NKT / 2; // 16
  __shared__ u16 LA[2 * 128 * 64];  // 32 KB
  __shared__ u16 LB[2 * 128 * 64];  // 32 KB
  int lin = blockIdx.y * 16 + blockIdx.x;
  int wid = (lin & 7) * 64 + (lin >> 3);
  int m0 = (wid & 31) * 128;
  int n0 = (wid >> 5) * 128;
  int t = threadIdx.x, lane = t & 63, w = t >> 6;
  int l15 = lane & 15, lhi = lane >> 4;
  int wrow = w >> 1, wcol = w & 1;  // 2x2 waves; per-wave out 64x64
  int srow = t >> 3;                // 0..31
  int scol = ((t & 7) ^ (srow & 7)) * 8;

#define STG_A(TILE, IDX) do {                                                      \
    int kb_ = ((TILE) < NKT ? (TILE) : NKT - 1) * 64;                              \
    glds16(A + (long)(m0 + (IDX) * 32 + srow) * K + kb_ + scol,                    \
           LA + ((TILE) & 1) * 8192 + (IDX) * 2048 + w * 512);                     \
  } while (0)
#define STG_B(TILE, IDX) do {                                                      \
    int kb_ = ((TILE) < NKT ? (TILE) : NKT - 1) * 64;                              \
    glds16(Bt + (long)(n0 + (IDX) * 32 + srow) * K + kb_ + scol,                   \
           LB + ((TILE) & 1) * 8192 + (IDX) * 2048 + w * 512);                     \
  } while (0)

  bf16x8 af2[4][2], bfr0[2][2], bfr1[2][2];
  f32x4 acc[4][4] = {};

#define LDA_ALL(BUF) do {                                                          \
    _Pragma("unroll") for (int mi = 0; mi < 4; mi++) {                             \
      int rA = wrow * 64 + mi * 16 + l15;                                          \
      _Pragma("unroll") for (int kk = 0; kk < 2; kk++)                             \
        af2[mi][kk] = *(const bf16x8*)(LA + (BUF) * 8192 + rA * 64 +               \
                                       (((kk * 4 + lhi) ^ (rA & 7)) * 8));         \
    } } while (0)
#define LDB_FRAGS(BUF, QN, DST) do {                                               \
    _Pragma("unroll") for (int ni = 0; ni < 2; ni++) {                             \
      int rB = wcol * 64 + ((QN) * 2 + ni) * 16 + l15;                             \
      _Pragma("unroll") for (int kk = 0; kk < 2; kk++)                             \
        DST[ni][kk] = *(const bf16x8*)(LB + (BUF) * 8192 + rB * 64 +               \
                                       (((kk * 4 + lhi) ^ (rB & 7)) * 8));         \
    } } while (0)
#define MM2Q(QN, BF) do {                                                          \
    __builtin_amdgcn_s_setprio(1);                                                 \
    _Pragma("unroll") for (int mi = 0; mi < 4; mi++)                               \
    _Pragma("unroll") for (int ni = 0; ni < 2; ni++)                               \
    _Pragma("unroll") for (int kk = 0; kk < 2; kk++)                               \
      acc[mi][(QN) * 2 + ni] = __builtin_amdgcn_mfma_f32_16x16x32_bf16(            \
          af2[mi][kk], BF[ni][kk], acc[mi][(QN) * 2 + ni], 0, 0, 0);               \
    __builtin_amdgcn_s_setprio(0);                                                 \
  } while (0)
#define BAR __builtin_amdgcn_s_barrier()
#define LG0 do { asm volatile("s_waitcnt lgkmcnt(0)" ::: "memory");                \
                 __builtin_amdgcn_sched_barrier(0); } while (0)
#define VMW4 do { asm volatile("s_waitcnt vmcnt(4)" ::: "memory");                 \
                  __builtin_amdgcn_sched_barrier(0); } while (0)

  STG_A(0, 0); STG_A(0, 1); STG_A(0, 2); STG_A(0, 3);
  STG_B(0, 0); STG_B(0, 1); STG_B(0, 2); STG_B(0, 3);
  STG_B(1, 0); STG_B(1, 1); STG_B(1, 2); STG_B(1, 3);
  VMW4; BAR;

  for (int it = 0; it < NIT; it++) {
    int k1 = 2 * it + 1, k2 = 2 * it + 2, k3 = 2 * it + 3;
    LDA_ALL(0); LDB_FRAGS(0, 0, bfr0);
    STG_A(k1, 0); STG_A(k1, 1); STG_A(k1, 2); STG_A(k1, 3);
    BAR; LG0; MM2Q(0, bfr0); BAR;                                    // phA
    LDB_FRAGS(0, 1, bfr1);
    STG_B(k2, 0); STG_B(k2, 1); STG_B(k2, 2); STG_B(k2, 3);
    BAR; LG0; MM2Q(1, bfr1);
    VMW4;  // completes B(k1)+A(k1) (consumed at phC)
    BAR;                                                             // phB
    LDA_ALL(1); LDB_FRAGS(1, 0, bfr0);
    STG_A(k2, 0); STG_A(k2, 1); STG_A(k2, 2); STG_A(k2, 3);
    BAR; LG0; MM2Q(0, bfr0); BAR;                                    // phC
    LDB_FRAGS(1, 1, bfr1);
    STG_B(k3, 0); STG_B(k3, 1); STG_B(k3, 2); STG_B(k3, 3);
    BAR; LG0; MM2Q(1, bfr1);
    VMW4;  // completes B(k2)+A(k2)
    BAR;                                                             // phD
  }
#undef STG_A
#undef STG_B
#undef LDA_ALL
#undef LDB_FRAGS
#undef MM2Q
#undef BAR
#undef LG0
#undef VMW4

#pragma unroll
  for (int mi = 0; mi < 4; mi++)
#pragma unroll
    for (int ni = 0; ni < 4; ni++) {
      int col = n0 + wcol * 64 + ni * 16 + l15;
      float bv = bias[col];
#pragma unroll
      for (int r = 0; r < 4; r++) {
        int row = m0 + wrow * 64 + mi * 16 + lhi * 4 + r;
        Out[(long)row * N + col] = acc[mi][ni][r] + bv;
      }
    }
}

// ---------------- flash attention: 1 q-tile per block, LPT dispatch (R15-best, reverted) ----------------
__global__ __launch_bounds__(256) void k_attn(const u16* __restrict__ Qb,
                                              const u16* __restrict__ Kb,
                                              const u16* __restrict__ Vt,
                                              const float* __restrict__ mask,
                                              u16* __restrict__ Ao) {
  constexpr int NT = SEQ / 64;  // 32
  int bh = blockIdx.x;          // b*NH + h
  int qt = (NT - 1) - blockIdx.y;  // longest first across all heads
  int t = threadIdx.x, w = t >> 6, lane = t & 63;
  int l15 = lane & 15, lhi = lane >> 4;
  int b = bh >> 4, h = bh & 15;
  const u16* Qh = Qb + (long)bh * SEQ * HD;
  const u16* Kh = Kb + (long)bh * SEQ * HD;
  const u16* Vh = Vt + (long)bh * HD * SEQ;
  const float* mh = mask + h * SEQ;

  __shared__ u16 Ks[2][64 * 128];   // 32 KB
  __shared__ u16 Vs[2][128 * 64];   // 32 KB
  __shared__ u16 p_lds[4 * 16 * 64];
  u16* pw = p_lds + w * (16 * 64);

  int krow[4], kcolS[4], vrow[4], vcolS[4];
#pragma unroll
  for (int i = 0; i < 4; i++) {
    int c = i * 256 + t;
    krow[i] = c >> 4; kcolS[i] = ((c & 15) ^ ((c >> 4) & 7)) * 8;   // K: 64 x 128
    vrow[i] = c >> 3; vcolS[i] = ((c & 7) ^ ((c >> 3) & 7)) * 8;    // V: 128 x 64
  }

#define STAGE(KT, BUF) do {                                                        \
    int kb_ = (KT) * 64;                                                           \
    _Pragma("unroll") for (int i = 0; i < 4; i++)                                  \
      glds16(Kh + (long)(kb_ + krow[i]) * HD + kcolS[i],                           \
             &Ks[BUF][(i * 256 + w * 64) * 8]);                                    \
    _Pragma("unroll") for (int i = 0; i < 4; i++)                                  \
      glds16(Vh + (long)vrow[i] * SEQ + kb_ + vcolS[i],                            \
             &Vs[BUF][(i * 256 + w * 64) * 8]);                                    \
  } while (0)

  const float sm_scale = 0.08838834764831845f;  // 1/sqrt(128)
  int q0 = qt * 64 + w * 16;
  int nt = qt + 1;

  bf16x8 qf[4];
#pragma unroll
  for (int kc = 0; kc < 4; kc++)
    qf[kc] = *(const bf16x8*)(Qh + (long)(q0 + l15) * HD + kc * 32 + lhi * 8);

  int rowr[4];
#pragma unroll
  for (int r = 0; r < 4; r++) rowr[r] = q0 + lhi * 4 + r;

  float mrun[4], lrun[4];
  f32x4 oacc[8] = {};
#pragma unroll
  for (int r = 0; r < 4; r++) { mrun[r] = -1e30f; lrun[r] = 0.f; }

  STAGE(0, 0);
  __syncthreads();  // drains vmcnt: tile 0 resident

  for (int kt = 0; kt < nt; kt++) {
    int cur = kt & 1;
    if (kt + 1 < nt) STAGE(kt + 1, cur ^ 1);  // async into other buffer
    bool diag = (kt == nt - 1);
    int kb = kt * 64;
    const u16* Ksg = Ks[cur];
    const u16* Vsg = Vs[cur];
    float bvv[4];
#pragma unroll
    for (int cb = 0; cb < 4; cb++) bvv[cb] = mh[kb + cb * 16 + l15];
    f32x4 sc[4] = {};
    __builtin_amdgcn_s_setprio(1);
#pragma unroll
    for (int kc = 0; kc < 4; kc++)
#pragma unroll
      for (int cb = 0; cb < 4; cb++) {
        int rr = cb * 16 + l15;
        bf16x8 kf = *(const bf16x8*)(Ksg + rr * 128 + ((kc * 32 + lhi * 8) ^ ((rr & 7) << 3)));
        sc[cb] = __builtin_amdgcn_mfma_f32_16x16x32_bf16(qf[kc], kf, sc[cb], 0, 0, 0);
      }
    __builtin_amdgcn_s_setprio(0);
    float p[4][4], tmax[4];
#pragma unroll
    for (int cb = 0; cb < 4; cb++) {
      int col = kb + cb * 16 + l15;
#pragma unroll
      for (int r = 0; r < 4; r++) {
        float v = sc[cb][r] * sm_scale + bvv[cb];
        if (diag) v = (col <= rowr[r]) ? v : -1e30f;
        p[cb][r] = v;
      }
    }
#pragma unroll
    for (int r = 0; r < 4; r++)
      tmax[r] = fmaxf(fmaxf(p[0][r], p[1][r]), fmaxf(p[2][r], p[3][r]));
    float alpha[4];
#pragma unroll
    for (int r = 0; r < 4; r++) {
      float v = tmax[r];
      v = fmaxf(v, __shfl_xor(v, 1));
      v = fmaxf(v, __shfl_xor(v, 2));
      v = fmaxf(v, __shfl_xor(v, 4));
      v = fmaxf(v, __shfl_xor(v, 8));
      float mnew = fmaxf(mrun[r], v);
      alpha[r] = __expf(mrun[r] - mnew);
      mrun[r] = mnew;
      float s = 0.f;
#pragma unroll
      for (int cb = 0; cb < 4; cb++) {
        float e = __expf(p[cb][r] - mnew);
        p[cb][r] = e;
        s += e;
      }
      s += __shfl_xor(s, 1); s += __shfl_xor(s, 2);
      s += __shfl_xor(s, 4); s += __shfl_xor(s, 8);
      lrun[r] = lrun[r] * alpha[r] + s;
    }
#pragma unroll
    for (int nb = 0; nb < 8; nb++)
#pragma unroll
      for (int r = 0; r < 4; r++) oacc[nb][r] *= alpha[r];
#pragma unroll
    for (int cb = 0; cb < 4; cb++)
#pragma unroll
      for (int r = 0; r < 4; r++) {
        int rr = lhi * 4 + r;
        pw[(rr * 64 + cb * 16 + l15) ^ ((rr & 7) << 3)] = f2bf(p[cb][r]);
      }
    asm volatile("s_waitcnt lgkmcnt(0)" ::: "memory");
    bf16x8 pa0 = *(const bf16x8*)(pw + ((l15 * 64 + lhi * 8) ^ ((l15 & 7) << 3)));
    bf16x8 pa1 = *(const bf16x8*)(pw + ((l15 * 64 + 32 + lhi * 8) ^ ((l15 & 7) << 3)));
    __builtin_amdgcn_s_setprio(1);
#pragma unroll
    for (int nb = 0; nb < 8; nb++) {
      int rr = nb * 16 + l15;
      bf16x8 vf0 = *(const bf16x8*)(Vsg + rr * 64 + ((lhi * 8) ^ ((rr & 7) << 3)));
      bf16x8 vf1 = *(const bf16x8*)(Vsg + rr * 64 + ((32 + lhi * 8) ^ ((rr & 7) << 3)));
      oacc[nb] = __builtin_amdgcn_mfma_f32_16x16x32_bf16(pa0, vf0, oacc[nb], 0, 0, 0);
      oacc[nb] = __builtin_amdgcn_mfma_f32_16x16x32_bf16(pa1, vf1, oacc[nb], 0, 0, 0);
    }
    __builtin_amdgcn_s_setprio(0);
    __syncthreads();  // all reads of buf cur done; drains staged loads for buf cur^1
  }
#pragma unroll
  for (int nb = 0; nb < 8; nb++)
#pragma unroll
    for (int r = 0; r < 4; r++) {
      int row = q0 + lhi * 4 + r;
      float v = oacc[nb][r] / lrun[r];
      Ao[((long)(b * SEQ + row)) * DM + h * HD + nb * 16 + l15] = f2bf(v);
    }
#undef STAGE
}

// ---------------- launcher ----------------
extern "C" void kernel_launch(void* const* d_in, const int* in_sizes, int n_in,
                              void* d_out, int out_size, void* d_ws, size_t ws_size,
                              hipStream_t stream) {
  const float* x    = (const float*)d_in[0];
  const float* amsk = (const float*)d_in[1];
  const float* Wqkv = (const float*)d_in[2];
  const float* bqkv = (const float*)d_in[3];
  const float* Wout = (const float*)d_in[4];
  const float* bout = (const float*)d_in[5];
  float* out = (float*)d_out;

  char* ws = (char*)d_ws;
  u16* xb  = (u16*)(ws + 0);                   // [4096][2048]
  u16* WqT = (u16*)(ws + 16777216UL);          // [6144][2048]
  u16* WoT = (u16*)(ws + 41943040UL);          // [2048][2048]
  u16* Qb  = (u16*)(ws + 50331648UL);          // [B*H][S][HD]
  u16* Kb  = (u16*)(ws + 67108864UL);          // [B*H][S][HD]
  u16* Vt  = (u16*)(ws + 83886080UL);          // [B*H][HD][S]
  u16* Ao  = (u16*)(ws + 100663296UL);         // [4096][2048]

  k_cvt<<<8192, 256, 0, stream>>>(x, xb, (MROWS * DM) / 4);
  k_transpose<<<dim3(N3 / 32, DM / 32), 256, 0, stream>>>(Wqkv, WqT, DM, N3);
  k_transpose<<<dim3(DM / 32, DM / 32), 256, 0, stream>>>(Wout, WoT, DM, DM);
  k_gemm_qkv<<<dim3(32, 32), 256, 0, stream>>>(xb, WqT, bqkv, Qb, Kb, Vt);
  k_attn<<<dim3(BATCH * NH, SEQ / 64), 256, 0, stream>>>(Qb, Kb, Vt, amsk, Ao);
  k_gemm_out<<<dim3(16, 32), 256, 0, stream>>>(Ao, WoT, bout, out);
}

// Round 18
// 275.508 us; speedup vs baseline: 1.0390x; 1.0139x over previous
//
#include <hip/hip_runtime.h>
#include <hip/hip_bf16.h>

typedef __bf16 bf16x8 __attribute__((ext_vector_type(8)));
typedef float f32x4 __attribute__((ext_vector_type(4)));
typedef unsigned short u16;

constexpr int BATCH = 2, SEQ = 2048, DM = 2048, NH = 16, HD = 128;
constexpr int N3 = 3 * DM;          // 6144
constexpr int MROWS = BATCH * SEQ;  // 4096

__device__ __forceinline__ u16 f2bf(float f) {
  unsigned u = __builtin_bit_cast(unsigned, f);
  unsigned r = 0x7FFFu + ((u >> 16) & 1u);
  return (u16)((u + r) >> 16);
}

// async global->LDS, 16B per lane; LDS dest = wave-uniform base + lane*16
__device__ __forceinline__ void glds16(const u16* g, u16* l) {
  __builtin_amdgcn_global_load_lds(
      (const __attribute__((address_space(1))) unsigned*)(const void*)g,
      (__attribute__((address_space(3))) unsigned*)(void*)l, 16, 0, 0);
}

// ---------------- fused pre-pass: cvt(x) + transpose(Wqkv) + transpose(Wout) ----------------
// One launch; blocks partitioned: [0,8192) cvt, [8192,20480) Wqkv 192x64 tiles,
// [20480,24576) Wout 64x64 tiles. All three jobs are HBM-bound and independent.
__global__ __launch_bounds__(256) void k_pre(const float* __restrict__ x,
                                             u16* __restrict__ xb,
                                             const float* __restrict__ Wqkv,
                                             u16* __restrict__ WqT,
                                             const float* __restrict__ Wout,
                                             u16* __restrict__ WoT) {
  __shared__ float tile[32][33];
  int bid = blockIdx.x;
  if (bid < 8192) {
    int i = bid * 256 + threadIdx.x;  // n4 = 2097152 exactly
    float4 v = reinterpret_cast<const float4*>(x)[i];
    ushort4 o;
    o.x = f2bf(v.x); o.y = f2bf(v.y); o.z = f2bf(v.z); o.w = f2bf(v.w);
    reinterpret_cast<ushort4*>(xb)[i] = o;
    return;
  }
  const float* in; u16* out; int K, N, bx, by;
  if (bid < 20480) {
    int i = bid - 8192;  // Wqkv: [2048][6144] -> [6144][2048]
    in = Wqkv; out = WqT; K = DM; N = N3;
    bx = i % 192; by = i / 192;
  } else {
    int i = bid - 20480; // Wout: [2048][2048] -> [2048][2048]
    in = Wout; out = WoT; K = DM; N = DM;
    bx = i & 63; by = i >> 6;
  }
  int n0 = bx * 32, k0 = by * 32;
  int tx = threadIdx.x & 31, ty = threadIdx.x >> 5;  // 32 x 8
#pragma unroll
  for (int r = ty; r < 32; r += 8) tile[r][tx] = in[(long)(k0 + r) * N + n0 + tx];
  __syncthreads();
#pragma unroll
  for (int r = ty; r < 32; r += 8) out[(long)(n0 + r) * K + k0 + tx] = f2bf(tile[tx][r]);
}

// ---------------- QKV GEMM: 128x192 tile, BK=64, 4 waves, 4-PHASE, 2 blocks/CU ----------------
__global__ __launch_bounds__(256, 2) void k_gemm_qkv(const u16* __restrict__ A,
                                                     const u16* __restrict__ Bt,
                                                     const float* __restrict__ bias,
                                                     u16* __restrict__ Qb, u16* __restrict__ Kb,
                                                     u16* __restrict__ Vt) {
  constexpr int K = DM;        // 2048
  constexpr int NKT = K / 64;  // 32 K-tiles
  constexpr int NIT = NKT / 2; // 16 iterations
  __shared__ u16 LA[2 * 128 * 64];  // 32 KB
  __shared__ u16 LB[2 * 192 * 64];  // 48 KB
  int lin = blockIdx.y * 32 + blockIdx.x;
  int wid = (lin & 7) * 128 + (lin >> 3);
  int m0 = (wid & 31) * 128;
  int n0 = (wid >> 5) * 192;
  int t = threadIdx.x, lane = t & 63, w = t >> 6;
  int l15 = lane & 15, lhi = lane >> 4;
  int wrow = w >> 1, wcol = w & 1;  // 2x2 wave grid; per-wave out 64x96
  int srow = t >> 3;                       // 0..31
  int scol = ((t & 7) ^ (srow & 7)) * 8;

#define STG_A(TILE, IDX) do {                                                      \
    int kb_ = ((TILE) < NKT ? (TILE) : NKT - 1) * 64;                              \
    glds16(A + (long)(m0 + (IDX) * 32 + srow) * K + kb_ + scol,                    \
           LA + ((TILE) & 1) * 8192 + (IDX) * 2048 + w * 512);                     \
  } while (0)
#define STG_B(TILE, IDX) do {                                                      \
    int kb_ = ((TILE) < NKT ? (TILE) : NKT - 1) * 64;                              \
    glds16(Bt + (long)(n0 + (IDX) * 32 + srow) * K + kb_ + scol,                   \
           LB + ((TILE) & 1) * 12288 + (IDX) * 2048 + w * 512);                    \
  } while (0)

  bf16x8 af2[4][2], bfr0[3][2], bfr1[3][2];
  f32x4 acc[4][6] = {};

#define LDA_ALL(BUF) do {                                                          \
    _Pragma("unroll") for (int mi = 0; mi < 4; mi++) {                             \
      int rA = wrow * 64 + mi * 16 + l15;                                          \
      _Pragma("unroll") for (int kk = 0; kk < 2; kk++)                             \
        af2[mi][kk] = *(const bf16x8*)(LA + (BUF) * 8192 + rA * 64 +               \
                                       (((kk * 4 + lhi) ^ (rA & 7)) * 8));         \
    } } while (0)
#define LDB_FRAGS(BUF, QN, DST) do {                                               \
    _Pragma("unroll") for (int ni = 0; ni < 3; ni++) {                             \
      int rB = wcol * 96 + ((QN) * 3 + ni) * 16 + l15;                             \
      _Pragma("unroll") for (int kk = 0; kk < 2; kk++)                             \
        DST[ni][kk] = *(const bf16x8*)(LB + (BUF) * 12288 + rB * 64 +              \
                                       (((kk * 4 + lhi) ^ (rB & 7)) * 8));         \
    } } while (0)
#define MM2Q(QN, BF) do {                                                          \
    __builtin_amdgcn_s_setprio(1);                                                 \
    _Pragma("unroll") for (int mi = 0; mi < 4; mi++)                               \
    _Pragma("unroll") for (int ni = 0; ni < 3; ni++)                               \
    _Pragma("unroll") for (int kk = 0; kk < 2; kk++)                               \
      acc[mi][(QN) * 3 + ni] = __builtin_amdgcn_mfma_f32_16x16x32_bf16(            \
          af2[mi][kk], BF[ni][kk], acc[mi][(QN) * 3 + ni], 0, 0, 0);               \
    __builtin_amdgcn_s_setprio(0);                                                 \
  } while (0)
#define BAR __builtin_amdgcn_s_barrier()
#define LG0 do { asm volatile("s_waitcnt lgkmcnt(0)" ::: "memory");                \
                 __builtin_amdgcn_sched_barrier(0); } while (0)
#define VMW6 do { asm volatile("s_waitcnt vmcnt(6)" ::: "memory");                 \
                  __builtin_amdgcn_sched_barrier(0); } while (0)

  STG_A(0, 0); STG_A(0, 1); STG_A(0, 2); STG_A(0, 3);
  STG_B(0, 0); STG_B(0, 1); STG_B(0, 2); STG_B(0, 3); STG_B(0, 4); STG_B(0, 5);
  STG_B(1, 0); STG_B(1, 1); STG_B(1, 2); STG_B(1, 3); STG_B(1, 4); STG_B(1, 5);
  VMW6; BAR;

  for (int it = 0; it < NIT; it++) {
    int k1 = 2 * it + 1, k2 = 2 * it + 2, k3 = 2 * it + 3;
    LDA_ALL(0); LDB_FRAGS(0, 0, bfr0);
    STG_A(k1, 0); STG_A(k1, 1); STG_A(k1, 2); STG_A(k1, 3);
    BAR; LG0; MM2Q(0, bfr0); BAR;                                    // phA
    LDB_FRAGS(0, 1, bfr1);
    STG_B(k2, 0); STG_B(k2, 1); STG_B(k2, 2);
    STG_B(k2, 3); STG_B(k2, 4); STG_B(k2, 5);
    BAR; LG0; MM2Q(1, bfr1);
    VMW6;  // completes B(k1)+A(k1) (consumed at phC)
    BAR;                                                             // phB
    LDA_ALL(1); LDB_FRAGS(1, 0, bfr0);
    STG_A(k2, 0); STG_A(k2, 1); STG_A(k2, 2); STG_A(k2, 3);
    BAR; LG0; MM2Q(0, bfr0); BAR;                                    // phC
    LDB_FRAGS(1, 1, bfr1);
    STG_B(k3, 0); STG_B(k3, 1); STG_B(k3, 2);
    STG_B(k3, 3); STG_B(k3, 4); STG_B(k3, 5);
    BAR; LG0; MM2Q(1, bfr1);
    VMW6;  // completes B(k2)+A(k2) for next iter's phA
    BAR;                                                             // phD
  }
#undef STG_A
#undef STG_B
#undef LDA_ALL
#undef LDB_FRAGS
#undef MM2Q
#undef BAR
#undef LG0
#undef VMW6

#pragma unroll
  for (int mi = 0; mi < 4; mi++)
#pragma unroll
    for (int ni = 0; ni < 6; ni++) {
      int col = n0 + wcol * 96 + ni * 16 + l15;
      float bv = bias[col];
      int sec = col >> 11, dn = col & 2047, h = dn >> 7, hd = dn & 127;
#pragma unroll
      for (int r = 0; r < 4; r++) {
        int row = m0 + wrow * 64 + mi * 16 + lhi * 4 + r;
        int bb = row >> 11, ss = row & 2047;
        u16 val = f2bf(acc[mi][ni][r] + bv);
        if (sec == 0)
          Qb[(((long)(bb * NH + h)) * SEQ + ss) * HD + hd] = val;
        else if (sec == 1)
          Kb[(((long)(bb * NH + h)) * SEQ + ss) * HD + hd] = val;
        else
          Vt[(((long)(bb * NH + h)) * HD + hd) * SEQ + ss] = val;
      }
    }
}

// ---------------- output GEMM: 128x128 tile, BK=64, 4 waves, 4-PHASE, 2 blocks/CU ----------------
__global__ __launch_bounds__(256, 2) void k_gemm_out(const u16* __restrict__ A,
                                                     const u16* __restrict__ Bt,
                                                     const float* __restrict__ bias,
                                                     float* __restrict__ Out) {
  constexpr int K = DM, N = DM;
  constexpr int NKT = K / 64;  // 32
  constexpr int NIT = NKT / 2; // 16
  __shared__ u16 LA[2 * 128 * 64];  // 32 KB
  __shared__ u16 LB[2 * 128 * 64];  // 32 KB
  int lin = blockIdx.y * 16 + blockIdx.x;
  int wid = (lin & 7) * 64 + (lin >> 3);
  int m0 = (wid & 31) * 128;
  int n0 = (wid >> 5) * 128;
  int t = threadIdx.x, lane = t & 63, w = t >> 6;
  int l15 = lane & 15, lhi = lane >> 4;
  int wrow = w >> 1, wcol = w & 1;  // 2x2 waves; per-wave out 64x64
  int srow = t >> 3;                // 0..31
  int scol = ((t & 7) ^ (srow & 7)) * 8;

#define STG_A(TILE, IDX) do {                                                      \
    int kb_ = ((TILE) < NKT ? (TILE) : NKT - 1) * 64;                              \
    glds16(A + (long)(m0 + (IDX) * 32 + srow) * K + kb_ + scol,                    \
           LA + ((TILE) & 1) * 8192 + (IDX) * 2048 + w * 512);                     \
  } while (0)
#define STG_B(TILE, IDX) do {                                                      \
    int kb_ = ((TILE) < NKT ? (TILE) : NKT - 1) * 64;                              \
    glds16(Bt + (long)(n0 + (IDX) * 32 + srow) * K + kb_ + scol,                   \
           LB + ((TILE) & 1) * 8192 + (IDX) * 2048 + w * 512);                     \
  } while (0)

  bf16x8 af2[4][2], bfr0[2][2], bfr1[2][2];
  f32x4 acc[4][4] = {};

#define LDA_ALL(BUF) do {                                                          \
    _Pragma("unroll") for (int mi = 0; mi < 4; mi++) {                             \
      int rA = wrow * 64 + mi * 16 + l15;                                          \
      _Pragma("unroll") for (int kk = 0; kk < 2; kk++)                             \
        af2[mi][kk] = *(const bf16x8*)(LA + (BUF) * 8192 + rA * 64 +               \
                                       (((kk * 4 + lhi) ^ (rA & 7)) * 8));         \
    } } while (0)
#define LDB_FRAGS(BUF, QN, DST) do {                                               \
    _Pragma("unroll") for (int ni = 0; ni < 2; ni++) {                             \
      int rB = wcol * 64 + ((QN) * 2 + ni) * 16 + l15;                             \
      _Pragma("unroll") for (int kk = 0; kk < 2; kk++)                             \
        DST[ni][kk] = *(const bf16x8*)(LB + (BUF) * 8192 + rB * 64 +               \
                                       (((kk * 4 + lhi) ^ (rB & 7)) * 8));         \
    } } while (0)
#define MM2Q(QN, BF) do {                                                          \
    __builtin_amdgcn_s_setprio(1);                                                 \
    _Pragma("unroll") for (int mi = 0; mi < 4; mi++)                               \
    _Pragma("unroll") for (int ni = 0; ni < 2; ni++)                               \
    _Pragma("unroll") for (int kk = 0; kk < 2; kk++)                               \
      acc[mi][(QN) * 2 + ni] = __builtin_amdgcn_mfma_f32_16x16x32_bf16(            \
          af2[mi][kk], BF[ni][kk], acc[mi][(QN) * 2 + ni], 0, 0, 0);               \
    __builtin_amdgcn_s_setprio(0);                                                 \
  } while (0)
#define BAR __builtin_amdgcn_s_barrier()
#define LG0 do { asm volatile("s_waitcnt lgkmcnt(0)" ::: "memory");                \
                 __builtin_amdgcn_sched_barrier(0); } while (0)
#define VMW4 do { asm volatile("s_waitcnt vmcnt(4)" ::: "memory");                 \
                  __builtin_amdgcn_sched_barrier(0); } while (0)

  STG_A(0, 0); STG_A(0, 1); STG_A(0, 2); STG_A(0, 3);
  STG_B(0, 0); STG_B(0, 1); STG_B(0, 2); STG_B(0, 3);
  STG_B(1, 0); STG_B(1, 1); STG_B(1, 2); STG_B(1, 3);
  VMW4; BAR;

  for (int it = 0; it < NIT; it++) {
    int k1 = 2 * it + 1, k2 = 2 * it + 2, k3 = 2 * it + 3;
    LDA_ALL(0); LDB_FRAGS(0, 0, bfr0);
    STG_A(k1, 0); STG_A(k1, 1); STG_A(k1, 2); STG_A(k1, 3);
    BAR; LG0; MM2Q(0, bfr0); BAR;                                    // phA
    LDB_FRAGS(0, 1, bfr1);
    STG_B(k2, 0); STG_B(k2, 1); STG_B(k2, 2); STG_B(k2, 3);
    BAR; LG0; MM2Q(1, bfr1);
    VMW4;  // completes B(k1)+A(k1) (consumed at phC)
    BAR;                                                             // phB
    LDA_ALL(1); LDB_FRAGS(1, 0, bfr0);
    STG_A(k2, 0); STG_A(k2, 1); STG_A(k2, 2); STG_A(k2, 3);
    BAR; LG0; MM2Q(0, bfr0); BAR;                                    // phC
    LDB_FRAGS(1, 1, bfr1);
    STG_B(k3, 0); STG_B(k3, 1); STG_B(k3, 2); STG_B(k3, 3);
    BAR; LG0; MM2Q(1, bfr1);
    VMW4;  // completes B(k2)+A(k2)
    BAR;                                                             // phD
  }
#undef STG_A
#undef STG_B
#undef LDA_ALL
#undef LDB_FRAGS
#undef MM2Q
#undef BAR
#undef LG0
#undef VMW4

#pragma unroll
  for (int mi = 0; mi < 4; mi++)
#pragma unroll
    for (int ni = 0; ni < 4; ni++) {
      int col = n0 + wcol * 64 + ni * 16 + l15;
      float bv = bias[col];
#pragma unroll
      for (int r = 0; r < 4; r++) {
        int row = m0 + wrow * 64 + mi * 16 + lhi * 4 + r;
        Out[(long)row * N + col] = acc[mi][ni][r] + bv;
      }
    }
}

// ---------------- flash attention: 1 q-tile per block, LPT dispatch ----------------
__global__ __launch_bounds__(256) void k_attn(const u16* __restrict__ Qb,
                                              const u16* __restrict__ Kb,
                                              const u16* __restrict__ Vt,
                                              const float* __restrict__ mask,
                                              u16* __restrict__ Ao) {
  constexpr int NT = SEQ / 64;  // 32
  int bh = blockIdx.x;          // b*NH + h
  int qt = (NT - 1) - blockIdx.y;  // longest first across all heads
  int t = threadIdx.x, w = t >> 6, lane = t & 63;
  int l15 = lane & 15, lhi = lane >> 4;
  int b = bh >> 4, h = bh & 15;
  const u16* Qh = Qb + (long)bh * SEQ * HD;
  const u16* Kh = Kb + (long)bh * SEQ * HD;
  const u16* Vh = Vt + (long)bh * HD * SEQ;
  const float* mh = mask + h * SEQ;

  __shared__ u16 Ks[2][64 * 128];   // 32 KB
  __shared__ u16 Vs[2][128 * 64];   // 32 KB
  __shared__ u16 p_lds[4 * 16 * 64];
  u16* pw = p_lds + w * (16 * 64);

  int krow[4], kcolS[4], vrow[4], vcolS[4];
#pragma unroll
  for (int i = 0; i < 4; i++) {
    int c = i * 256 + t;
    krow[i] = c >> 4; kcolS[i] = ((c & 15) ^ ((c >> 4) & 7)) * 8;   // K: 64 x 128
    vrow[i] = c >> 3; vcolS[i] = ((c & 7) ^ ((c >> 3) & 7)) * 8;    // V: 128 x 64
  }

#define STAGE(KT, BUF) do {                                                        \
    int kb_ = (KT) * 64;                                                           \
    _Pragma("unroll") for (int i = 0; i < 4; i++)                                  \
      glds16(Kh + (long)(kb_ + krow[i]) * HD + kcolS[i],                           \
             &Ks[BUF][(i * 256 + w * 64) * 8]);                                    \
    _Pragma("unroll") for (int i = 0; i < 4; i++)                                  \
      glds16(Vh + (long)vrow[i] * SEQ + kb_ + vcolS[i],                            \
             &Vs[BUF][(i * 256 + w * 64) * 8]);                                    \
  } while (0)

  const float sm_scale = 0.08838834764831845f;  // 1/sqrt(128)
  int q0 = qt * 64 + w * 16;
  int nt = qt + 1;

  bf16x8 qf[4];
#pragma unroll
  for (int kc = 0; kc < 4; kc++)
    qf[kc] = *(const bf16x8*)(Qh + (long)(q0 + l15) * HD + kc * 32 + lhi * 8);

  int rowr[4];
#pragma unroll
  for (int r = 0; r < 4; r++) rowr[r] = q0 + lhi * 4 + r;

  float mrun[4], lrun[4];
  f32x4 oacc[8] = {};
#pragma unroll
  for (int r = 0; r < 4; r++) { mrun[r] = -1e30f; lrun[r] = 0.f; }

  STAGE(0, 0);
  __syncthreads();  // drains vmcnt: tile 0 resident

  for (int kt = 0; kt < nt; kt++) {
    int cur = kt & 1;
    if (kt + 1 < nt) STAGE(kt + 1, cur ^ 1);  // async into other buffer
    bool diag = (kt == nt - 1);
    int kb = kt * 64;
    const u16* Ksg = Ks[cur];
    const u16* Vsg = Vs[cur];
    float bvv[4];
#pragma unroll
    for (int cb = 0; cb < 4; cb++) bvv[cb] = mh[kb + cb * 16 + l15];
    f32x4 sc[4] = {};
    __builtin_amdgcn_s_setprio(1);
#pragma unroll
    for (int kc = 0; kc < 4; kc++)
#pragma unroll
      for (int cb = 0; cb < 4; cb++) {
        int rr = cb * 16 + l15;
        bf16x8 kf = *(const bf16x8*)(Ksg + rr * 128 + ((kc * 32 + lhi * 8) ^ ((rr & 7) << 3)));
        sc[cb] = __builtin_amdgcn_mfma_f32_16x16x32_bf16(qf[kc], kf, sc[cb], 0, 0, 0);
      }
    __builtin_amdgcn_s_setprio(0);
    float p[4][4], tmax[4];
#pragma unroll
    for (int cb = 0; cb < 4; cb++) {
      int col = kb + cb * 16 + l15;
#pragma unroll
      for (int r = 0; r < 4; r++) {
        float v = sc[cb][r] * sm_scale + bvv[cb];
        if (diag) v = (col <= rowr[r]) ? v : -1e30f;
        p[cb][r] = v;
      }
    }
#pragma unroll
    for (int r = 0; r < 4; r++)
      tmax[r] = fmaxf(fmaxf(p[0][r], p[1][r]), fmaxf(p[2][r], p[3][r]));
    float alpha[4];
#pragma unroll
    for (int r = 0; r < 4; r++) {
      float v = tmax[r];
      v = fmaxf(v, __shfl_xor(v, 1));
      v = fmaxf(v, __shfl_xor(v, 2));
      v = fmaxf(v, __shfl_xor(v, 4));
      v = fmaxf(v, __shfl_xor(v, 8));
      float mnew = fmaxf(mrun[r], v);
      alpha[r] = __expf(mrun[r] - mnew);
      mrun[r] = mnew;
      float s = 0.f;
#pragma unroll
      for (int cb = 0; cb < 4; cb++) {
        float e = __expf(p[cb][r] - mnew);
        p[cb][r] = e;
        s += e;
      }
      s += __shfl_xor(s, 1); s += __shfl_xor(s, 2);
      s += __shfl_xor(s, 4); s += __shfl_xor(s, 8);
      lrun[r] = lrun[r] * alpha[r] + s;
    }
#pragma unroll
    for (int nb = 0; nb < 8; nb++)
#pragma unroll
      for (int r = 0; r < 4; r++) oacc[nb][r] *= alpha[r];
#pragma unroll
    for (int cb = 0; cb < 4; cb++)
#pragma unroll
      for (int r = 0; r < 4; r++) {
        int rr = lhi * 4 + r;
        pw[(rr * 64 + cb * 16 + l15) ^ ((rr & 7) << 3)] = f2bf(p[cb][r]);
      }
    asm volatile("s_waitcnt lgkmcnt(0)" ::: "memory");
    bf16x8 pa0 = *(const bf16x8*)(pw + ((l15 * 64 + lhi * 8) ^ ((l15 & 7) << 3)));
    bf16x8 pa1 = *(const bf16x8*)(pw + ((l15 * 64 + 32 + lhi * 8) ^ ((l15 & 7) << 3)));
    __builtin_amdgcn_s_setprio(1);
#pragma unroll
    for (int nb = 0; nb < 8; nb++) {
      int rr = nb * 16 + l15;
      bf16x8 vf0 = *(const bf16x8*)(Vsg + rr * 64 + ((lhi * 8) ^ ((rr & 7) << 3)));
      bf16x8 vf1 = *(const bf16x8*)(Vsg + rr * 64 + ((32 + lhi * 8) ^ ((rr & 7) << 3)));
      oacc[nb] = __builtin_amdgcn_mfma_f32_16x16x32_bf16(pa0, vf0, oacc[nb], 0, 0, 0);
      oacc[nb] = __builtin_amdgcn_mfma_f32_16x16x32_bf16(pa1, vf1, oacc[nb], 0, 0, 0);
    }
    __builtin_amdgcn_s_setprio(0);
    __syncthreads();  // all reads of buf cur done; drains staged loads for buf cur^1
  }
#pragma unroll
  for (int nb = 0; nb < 8; nb++)
#pragma unroll
    for (int r = 0; r < 4; r++) {
      int row = q0 + lhi * 4 + r;
      float v = oacc[nb][r] / lrun[r];
      Ao[((long)(b * SEQ + row)) * DM + h * HD + nb * 16 + l15] = f2bf(v);
    }
#undef STAGE
}

// ---------------- launcher ----------------
extern "C" void kernel_launch(void* const* d_in, const int* in_sizes, int n_in,
                              void* d_out, int out_size, void* d_ws, size_t ws_size,
                              hipStream_t stream) {
  const float* x    = (const float*)d_in[0];
  const float* amsk = (const float*)d_in[1];
  const float* Wqkv = (const float*)d_in[2];
  const float* bqkv = (const float*)d_in[3];
  const float* Wout = (const float*)d_in[4];
  const float* bout = (const float*)d_in[5];
  float* out = (float*)d_out;

  char* ws = (char*)d_ws;
  u16* xb  = (u16*)(ws + 0);                   // [4096][2048]
  u16* WqT = (u16*)(ws + 16777216UL);          // [6144][2048]
  u16* WoT = (u16*)(ws + 41943040UL);          // [2048][2048]
  u16* Qb  = (u16*)(ws + 50331648UL);          // [B*H][S][HD]
  u16* Kb  = (u16*)(ws + 67108864UL);          // [B*H][S][HD]
  u16* Vt  = (u16*)(ws + 83886080UL);          // [B*H][HD][S]
  u16* Ao  = (u16*)(ws + 100663296UL);         // [4096][2048]

  k_pre<<<24576, 256, 0, stream>>>(x, xb, Wqkv, WqT, Wout, WoT);
  k_gemm_qkv<<<dim3(32, 32), 256, 0, stream>>>(xb, WqT, bqkv, Qb, Kb, Vt);
  k_attn<<<dim3(BATCH * NH, SEQ / 64), 256, 0, stream>>>(Qb, Kb, Vt, amsk, Ao);
  k_gemm_out<<<dim3(16, 32), 256, 0, stream>>>(Ao, WoT, bout, out);
}